// Round 1
// baseline (466.100 us; speedup 1.0000x reference)
//
#include <hip/hip_runtime.h>
#include <hip/hip_bf16.h>

// dendriticNet fused kernel, round 0 (correctness-first fused design).
// B=32768, H=256, out = [s0',s1',s2',i0',i1'] each (B,H) f32.
//
// Folding: out_s0 = 0.81*s0 + rd@(0.1 wpf0)^T + rs1@(0.08 wpb0)^T + ri0@(0.08 wpi0)^T
//          out_i0 = 0.81*i0 + rs0@(0.1 wip0)^T + 0.08*mean_row(rs1)
//          out_s1 = 0.81*s1 + rs0@(0.1 wpf1)^T + rs2@(0.08 wpb1)^T + ri1@(0.08 wpi1)^T
//          out_i1 = 0.81*i1 + rs1@(0.1 wip1)^T + 0.08*mean_row(rs2)
//          out_s2 = 0.89*s2 + rs1@(0.1 wpf2)^T
// Weights pre-scaled+bf16-converted into d_ws (9 * 256*256 bf16 = 1.18 MB).

#define HH 256
#define BM 32
#define ROWP 264                    // padded LDS row (bf16 elems), 16B-aligned, conflict-friendly
#define TILE_ELEMS (BM * ROWP)      // 8448 bf16 = 16896 B per tile
#define BHTOT ((size_t)32768 * 256)

typedef __bf16 bf16_t;
typedef __bf16 bf16x8 __attribute__((ext_vector_type(8)));
typedef float  f32x4  __attribute__((ext_vector_type(4)));

__device__ __forceinline__ float fast_tanh(float x) {
    // tanh(x) = 1 - 2/(exp(2x)+1); exact at +-inf, ~1ulp-ish, way below bf16 noise
    float e = __expf(2.0f * x);
    return 1.0f - 2.0f * __builtin_amdgcn_rcpf(e + 1.0f);
}

// Stage one BM x 256 f32 tile -> tanh -> bf16 LDS tile (padded rows).
// Optionally produce 0.08*mean_row(rho) into nudge[0..31].
__device__ __forceinline__ void stage_tile(const float* __restrict__ src,
                                           bf16_t* __restrict__ dst,
                                           int row0, int lane, int wv,
                                           float* __restrict__ nudge) {
#pragma unroll
    for (int it = 0; it < 8; ++it) {
        int row = wv + it * 4;                       // wave w handles rows w, w+4, ...
        const float4 v = *reinterpret_cast<const float4*>(
            src + (size_t)(row0 + row) * HH + lane * 4);
        float t0 = fast_tanh(v.x), t1 = fast_tanh(v.y);
        float t2 = fast_tanh(v.z), t3 = fast_tanh(v.w);
        union { bf16_t b[4]; unsigned long long u; } pk;
        pk.b[0] = (bf16_t)t0; pk.b[1] = (bf16_t)t1;
        pk.b[2] = (bf16_t)t2; pk.b[3] = (bf16_t)t3;
        *reinterpret_cast<unsigned long long*>(dst + row * ROWP + lane * 4) = pk.u;
        if (nudge) {                                  // full wave covers one row here
            float s = (t0 + t1) + (t2 + t3);
            s += __shfl_down(s, 32);
            s += __shfl_down(s, 16);
            s += __shfl_down(s, 8);
            s += __shfl_down(s, 4);
            s += __shfl_down(s, 2);
            s += __shfl_down(s, 1);
            if (lane == 0) nudge[row] = s * (0.08f / 256.0f);  // DT*GSOM*mean
        }
    }
}

// One K=256 GEMM segment: acc(32x[64-col slice]) += rho_tile @ Wg^T.
// A-frag: A[m=lane&15][k=(lane>>4)*8+j]; B-frag: B[k][n=lane&15], k=(lane>>4)*8+j.
__device__ __forceinline__ void gemm_seg(const bf16_t* __restrict__ sa,
                                         const bf16_t* __restrict__ wg,
                                         int lane, int wv, f32x4 acc[2][4]) {
    const int r = lane & 15, q = lane >> 4;
    const bf16_t* a0p = sa + r * ROWP + q * 8;
    const bf16_t* a1p = a0p + 16 * ROWP;
    const bf16_t* bp  = wg + (size_t)(wv * 64 + r) * HH + q * 8;
#pragma unroll 2
    for (int k0 = 0; k0 < HH; k0 += 32) {
        bf16x8 a0 = *reinterpret_cast<const bf16x8*>(a0p + k0);
        bf16x8 a1 = *reinterpret_cast<const bf16x8*>(a1p + k0);
#pragma unroll
        for (int nt = 0; nt < 4; ++nt) {
            bf16x8 b = *reinterpret_cast<const bf16x8*>(bp + nt * 16 * HH + k0);
            acc[0][nt] = __builtin_amdgcn_mfma_f32_16x16x32_bf16(a0, b, acc[0][nt], 0, 0, 0);
            acc[1][nt] = __builtin_amdgcn_mfma_f32_16x16x32_bf16(a1, b, acc[1][nt], 0, 0, 0);
        }
    }
}

// out = acc + c*raw (+ nudge[row]);  C-frag layout: col=lane&15, row=(lane>>4)*4+reg.
__device__ __forceinline__ void epilogue(f32x4 acc[2][4], const float* __restrict__ raw,
                                         float* __restrict__ outp, int row0, int lane, int wv,
                                         float c, const float* __restrict__ nudge) {
    const int cb = lane & 15, q = lane >> 4;
#pragma unroll
    for (int m = 0; m < 2; ++m) {
#pragma unroll
        for (int nt = 0; nt < 4; ++nt) {
            int col = wv * 64 + nt * 16 + cb;
#pragma unroll
            for (int rg = 0; rg < 4; ++rg) {
                int lrow = m * 16 + q * 4 + rg;
                size_t idx = (size_t)(row0 + lrow) * HH + col;
                float v = acc[m][nt][rg] + c * raw[idx];
                if (nudge) v += nudge[lrow];
                outp[idx] = v;
            }
        }
    }
}

struct WPtrs { const float* p[9]; };

// Pre-scale + convert the 9 weight matrices to bf16 into d_ws.
// order g: 0 wpf0(.1) 1 wpf1(.1) 2 wpf2(.1) 3 wpb0(.08) 4 wpb1(.08)
//          5 wip0(.1) 6 wip1(.1) 7 wpi0(.08) 8 wpi1(.08)
__global__ void prep_w(WPtrs wp, bf16_t* __restrict__ out) {
    const float scales[9] = {0.1f, 0.1f, 0.1f, 0.08f, 0.08f, 0.1f, 0.1f, 0.08f, 0.08f};
    int g  = blockIdx.x >> 6;
    int bi = blockIdx.x & 63;
    float sc = scales[g];
    int idx = (bi * 256 + threadIdx.x) * 4;
    float4 v = *reinterpret_cast<const float4*>(wp.p[g] + idx);
    union { bf16_t b[4]; unsigned long long u; } pk;
    pk.b[0] = (bf16_t)(v.x * sc); pk.b[1] = (bf16_t)(v.y * sc);
    pk.b[2] = (bf16_t)(v.z * sc); pk.b[3] = (bf16_t)(v.w * sc);
    *reinterpret_cast<unsigned long long*>(out + (size_t)g * 65536 + idx) = pk.u;
}

__global__ __launch_bounds__(256) void dendritic_main(
    const float* __restrict__ data, const float* __restrict__ s0,
    const float* __restrict__ s1,   const float* __restrict__ s2,
    const float* __restrict__ i0,   const float* __restrict__ i1,
    const bf16_t* __restrict__ wws, float* __restrict__ out)
{
    extern __shared__ char smem[];
    bf16_t* slot0 = (bf16_t*)smem;                 // rs0 (persistent)
    bf16_t* slot1 = slot0 + TILE_ELEMS;            // rs1 (persistent)
    bf16_t* slot2 = slot1 + TILE_ELEMS;            // streaming: rd, ri0, rs2, ri1
    float*  snudge = (float*)(slot2 + TILE_ELEMS); // [2][32]

    const int tid = threadIdx.x, lane = tid & 63, wv = tid >> 6;
    const int row0 = blockIdx.x * BM;

    stage_tile(s0,   slot0, row0, lane, wv, nullptr);
    stage_tile(s1,   slot1, row0, lane, wv, snudge);      // nudge0 = 0.08*mean(rs1)
    stage_tile(data, slot2, row0, lane, wv, nullptr);
    __syncthreads();

    f32x4 acc[2][4];
    const f32x4 z = {0.f, 0.f, 0.f, 0.f};

    // ---------- phase s0 -> out[0]
#pragma unroll
    for (int m = 0; m < 2; ++m) for (int nt = 0; nt < 4; ++nt) acc[m][nt] = z;
    gemm_seg(slot2, wws + 0 * 65536, lane, wv, acc);      // rd @ wpf0
    gemm_seg(slot1, wws + 3 * 65536, lane, wv, acc);      // rs1 @ wpb0
    __syncthreads();
    stage_tile(i0, slot2, row0, lane, wv, nullptr);       // ri0
    __syncthreads();
    gemm_seg(slot2, wws + 7 * 65536, lane, wv, acc);      // ri0 @ wpi0
    epilogue(acc, s0, out + 0 * BHTOT, row0, lane, wv, 0.81f, nullptr);

    // ---------- phase i0 -> out[3]
#pragma unroll
    for (int m = 0; m < 2; ++m) for (int nt = 0; nt < 4; ++nt) acc[m][nt] = z;
    gemm_seg(slot0, wws + 5 * 65536, lane, wv, acc);      // rs0 @ wip0
    epilogue(acc, i0, out + 3 * BHTOT, row0, lane, wv, 0.81f, snudge);

    // ---------- phase s1 -> out[1]
#pragma unroll
    for (int m = 0; m < 2; ++m) for (int nt = 0; nt < 4; ++nt) acc[m][nt] = z;
    gemm_seg(slot0, wws + 1 * 65536, lane, wv, acc);      // rs0 @ wpf1
    __syncthreads();
    stage_tile(s2, slot2, row0, lane, wv, snudge + 32);   // rs2, nudge1
    __syncthreads();
    gemm_seg(slot2, wws + 4 * 65536, lane, wv, acc);      // rs2 @ wpb1
    __syncthreads();
    stage_tile(i1, slot2, row0, lane, wv, nullptr);       // ri1
    __syncthreads();
    gemm_seg(slot2, wws + 8 * 65536, lane, wv, acc);      // ri1 @ wpi1
    epilogue(acc, s1, out + 1 * BHTOT, row0, lane, wv, 0.81f, nullptr);

    // ---------- phase i1 -> out[4]
#pragma unroll
    for (int m = 0; m < 2; ++m) for (int nt = 0; nt < 4; ++nt) acc[m][nt] = z;
    gemm_seg(slot1, wws + 6 * 65536, lane, wv, acc);      // rs1 @ wip1
    epilogue(acc, i1, out + 4 * BHTOT, row0, lane, wv, 0.81f, snudge + 32);

    // ---------- phase s2 -> out[2]
#pragma unroll
    for (int m = 0; m < 2; ++m) for (int nt = 0; nt < 4; ++nt) acc[m][nt] = z;
    gemm_seg(slot1, wws + 2 * 65536, lane, wv, acc);      // rs1 @ wpf2
    epilogue(acc, s2, out + 2 * BHTOT, row0, lane, wv, 0.89f, nullptr);
}

extern "C" void kernel_launch(void* const* d_in, const int* in_sizes, int n_in,
                              void* d_out, int out_size, void* d_ws, size_t ws_size,
                              hipStream_t stream) {
    const float* data = (const float*)d_in[0];
    const float* s0   = (const float*)d_in[1];
    const float* s1   = (const float*)d_in[2];
    const float* s2   = (const float*)d_in[3];
    const float* i0   = (const float*)d_in[4];
    const float* i1   = (const float*)d_in[5];

    WPtrs wp;
    for (int g = 0; g < 9; ++g) wp.p[g] = (const float*)d_in[6 + g];

    bf16_t* wws = (bf16_t*)d_ws;        // needs 9*65536*2 = 1,179,648 B of scratch
    float*  out = (float*)d_out;

    // convert + pre-scale weights (runs every call; d_ws is re-poisoned each launch)
    prep_w<<<576, 256, 0, stream>>>(wp, wws);

    // fused main kernel: 1024 blocks of 256 threads, 50,944 B dynamic LDS
    const int ldsBytes = 3 * TILE_ELEMS * 2 + 2 * 32 * 4;
    dendritic_main<<<1024, 256, ldsBytes, stream>>>(data, s0, s1, s2, i0, i1, wws, out);
}